// Round 7
// baseline (146.843 us; speedup 1.0000x reference)
//
#include <hip/hip_runtime.h>

// QuantumAttention: B=8, S=2048, E=8, H=2, D=4, NQ=8
//
// Accounting (R5..R11, rocprof-anchored): total = fill 40.5 + attn 25.9 +
// merge ~2.6 + ~5.8us per graph node x3. Broadcast mechanisms measured:
// LDS 25.9us < DPP-rotate ~39 (serial dep + wait-states) < readlane ~64
// (VALU->SGPR hazard). attn9 (M=2, LDS broadcast) is the keeper.
// R12: fuse merge into attn -> 2 nodes. Last-block pattern with SENTINEL
// FLAG STORES (no atomic-counter init needed: ws is re-poisoned each iter,
// poison != MAGIC). Group = (b,rt) = 16 blocks (2h x 8jw); member (h=1,
// jw=7) spins on the 15 flags (acquire, agent scope), then runs merge9's
// math bit-identically for its 128 tokens. Deadlock-free at ANY occupancy:
// <=128 spinners vs >=256 resident slots. Phase-1 math bit-identical.
//
// Quantum circuit closed-form: c_w = cos(tok[w]+tok[w%4]);
// z[0]=c1..c7, z[q>=1]=c0..cq. Softmax one-pass (scores bounded, fp32 safe);
// 0.5*log2(e) folded into Wq so inner exp is bare v_exp_f32 (exp2).

#define SS 2048
#define EE 8
#define MAGIC 0x7FA1B2C3u

// grid 2048: bid = b<<8 | h<<7 | rt<<3 | jw.  256 threads = 4 waves.
// Block: rows rt*128..+127 (2 per lane), j-window jw*256..+255 (64 per wave).
extern "C" __global__ __launch_bounds__(256, 8)
void qa_fused12(const float* __restrict__ x, const float* __restrict__ Wq,
                const float* __restrict__ Wk, const float* __restrict__ Wv,
                const float* __restrict__ Wo,
                float* __restrict__ wsD, float4* __restrict__ wsA,
                unsigned int* __restrict__ flags, float* __restrict__ out) {
    __shared__ float wrow[96];                    // wq'(scaled), wk, wv
    __shared__ __align__(16) float4 kv4[512];     // 256 j x {K4,V4} = 8 KB
    __shared__ float rden[3 * 128];               // waves 1..3 partials
    __shared__ __align__(16) float4 racc[3 * 128];// 6 KB
    __shared__ float wo[64];

    const int bid = blockIdx.x;
    const int jw = bid & 7, rt = (bid >> 3) & 15, h = (bid >> 7) & 1, b = bid >> 8;
    const int tid = threadIdx.x, lane = tid & 63, w = tid >> 6;
    const int gidx = b * 16 + rt;                 // 128 groups of 16 blocks
    const bool merger = (h == 1) && (jw == 7);    // memberIdx 15

    if (tid < 96) {
        const int grp = tid >> 5, d = (tid >> 3) & 3, e = tid & 7;
        const float* W = (grp == 0) ? Wq : (grp == 1 ? Wk : Wv);
        float val = W[(h * 4 + d) * EE + e];
        if (grp == 0) val *= 0.72134752044f;   // 0.5 * log2(e)
        wrow[tid] = val;
    }
    if (merger && tid >= 128 && tid < 192) wo[tid - 128] = Wo[tid - 128];
    __syncthreads();   // wrow ready

    // ---- stage K,V for the 256-j window (one j per thread) ----
    {
        const int j = jw * 256 + tid;
        const float* xp = x + ((size_t)(b * SS + j)) * EE;
        float xv[8];
        *(float4*)&xv[0] = *(const float4*)xp;
        *(float4*)&xv[4] = *(const float4*)(xp + 4);
        float kk[4], vv[4];
        #pragma unroll
        for (int d = 0; d < 4; ++d) {
            float sk = 0.f, sv = 0.f;
            #pragma unroll
            for (int e = 0; e < 8; ++e) {
                sk += xv[e] * wrow[32 + d * 8 + e];
                sv += xv[e] * wrow[64 + d * 8 + e];
            }
            kk[d] = sk; vv[d] = sv;
        }
        kv4[tid * 2]     = make_float4(kk[0], kk[1], kk[2], kk[3]);
        kv4[tid * 2 + 1] = make_float4(vv[0], vv[1], vv[2], vv[3]);
    }

    // ---- q' (log2-scaled) for this lane's 2 rows ----
    float q[2][4];
    const int row0 = rt * 128 + lane;
    #pragma unroll
    for (int m = 0; m < 2; ++m) {
        const float* xp = x + ((size_t)(b * SS + row0 + m * 64)) * EE;
        float xv[8];
        *(float4*)&xv[0] = *(const float4*)xp;
        *(float4*)&xv[4] = *(const float4*)(xp + 4);
        #pragma unroll
        for (int d = 0; d < 4; ++d) {
            float s = 0.f;
            #pragma unroll
            for (int e = 0; e < 8; ++e) s += xv[e] * wrow[d * 8 + e];
            q[m][d] = s;
        }
    }
    __syncthreads();   // kv4 ready

    // ---- 64-j slice for this wave, 2 rows per lane ----
    float den[2] = {};
    float acc[2][4] = {};
    const float4* kvp = &kv4[w * 128];
    #pragma unroll 2
    for (int jl = 0; jl < 64; ++jl) {
        const float4 kk = kvp[jl * 2];      // wave-broadcast
        const float4 vv = kvp[jl * 2 + 1];
        #pragma unroll
        for (int m = 0; m < 2; ++m) {
            const float s = q[m][0] * kk.x + q[m][1] * kk.y
                          + q[m][2] * kk.z + q[m][3] * kk.w;
            const float e = __builtin_amdgcn_exp2f(s);
            den[m] += e;
            acc[m][0] += e * vv.x; acc[m][1] += e * vv.y;
            acc[m][2] += e * vv.z; acc[m][3] += e * vv.w;
        }
    }

    // ---- single-stage reduce: waves 1..3 park, wave 0 merges + writes ----
    if (w > 0) {
        #pragma unroll
        for (int m = 0; m < 2; ++m) {
            rden[(w - 1) * 128 + lane + m * 64] = den[m];
            racc[(w - 1) * 128 + lane + m * 64] =
                make_float4(acc[m][0], acc[m][1], acc[m][2], acc[m][3]);
        }
    }
    __syncthreads();
    if (w == 0) {
        #pragma unroll
        for (int m = 0; m < 2; ++m) {
            const int r = lane + m * 64;
            float d = den[m] + rden[r] + rden[128 + r] + rden[256 + r];
            float4 a1 = racc[r], a2 = racc[128 + r], a3 = racc[256 + r];
            float4 a = make_float4(acc[m][0] + a1.x + a2.x + a3.x,
                                   acc[m][1] + a1.y + a2.y + a3.y,
                                   acc[m][2] + a1.z + a2.z + a3.z,
                                   acc[m][3] + a1.w + a2.w + a3.w);
            const size_t idx = ((size_t)((b * 2 + h) * 8 + jw)) * SS + row0 + m * 64;
            wsD[idx] = d;
            wsA[idx] = a;
        }
    }
    __syncthreads();   // wave0's ws stores issued before publication

    if (!merger) {
        if (tid == 0) {
            __threadfence();   // publish partials (device scope)
            __hip_atomic_store(&flags[gidx * 16 + (h * 8 + jw)], MAGIC,
                               __ATOMIC_RELEASE, __HIP_MEMORY_SCOPE_AGENT);
        }
        return;
    }

    // ---- merger: wait for the 15 sibling blocks ----
    if (tid < 15) {
        const unsigned int* f = &flags[gidx * 16 + tid];
        while (__hip_atomic_load(f, __ATOMIC_ACQUIRE,
                                 __HIP_MEMORY_SCOPE_AGENT) != MAGIC)
            __builtin_amdgcn_s_sleep(2);
    }
    __syncthreads();

    // ---- merge + quantum (bit-identical to merge9), 2 threads/token ----
    {
        const int s = rt * 128 + (tid >> 1);     // token row in this batch
        const int hh = tid & 1;
        const int g = b * SS + s;

        float dsum = 0.f, a0 = 0.f, a1 = 0.f, a2 = 0.f, a3 = 0.f;
        #pragma unroll
        for (int sl = 0; sl < 8; ++sl) {
            const size_t idx = ((size_t)((b * 2 + hh) * 8 + sl)) * SS + s;
            dsum += wsD[idx];
            const float4 p = wsA[idx];
            a0 += p.x; a1 += p.y; a2 += p.z; a3 += p.w;
        }
        const float inv = 1.f / dsum;
        float own[4] = {a0 * inv, a1 * inv, a2 * inv, a3 * inv};
        float oth[4];
        #pragma unroll
        for (int c = 0; c < 4; ++c) oth[c] = __shfl_xor(own[c], 1);

        float tok[8];
        #pragma unroll
        for (int c = 0; c < 4; ++c) {
            tok[c]     = hh ? oth[c] : own[c];
            tok[4 + c] = hh ? own[c] : oth[c];
        }

        float cc[8];
        #pragma unroll
        for (int ww = 0; ww < 8; ++ww) cc[ww] = __cosf(tok[ww] + tok[ww & 3]);

        float z[8];
        float p = 1.f;
        #pragma unroll
        for (int qq = 1; qq < 8; ++qq) { p *= cc[qq]; z[qq] = p; }
        z[0] = p;                       // c1..c7
        #pragma unroll
        for (int qq = 1; qq < 8; ++qq) z[qq] *= cc[0];   // c0..cq

        float y[4];
        #pragma unroll
        for (int f2 = 0; f2 < 4; ++f2) {
            float sum = 0.f;
            #pragma unroll
            for (int qq = 0; qq < 8; ++qq)
                sum += z[qq] * wo[(hh * 4 + f2) * 8 + qq];
            y[f2] = sum;
        }
        float4* op = (float4*)(out + (size_t)g * 8) + hh;
        *op = make_float4(y[0], y[1], y[2], y[3]);
    }
}

extern "C" void kernel_launch(void* const* d_in, const int* in_sizes, int n_in,
                              void* d_out, int out_size, void* d_ws, size_t ws_size,
                              hipStream_t stream) {
    const float* x  = (const float*)d_in[0];
    const float* Wq = (const float*)d_in[1];
    const float* Wk = (const float*)d_in[2];
    const float* Wv = (const float*)d_in[3];
    const float* Wo = (const float*)d_in[4];
    float* out = (float*)d_out;

    // ws layout: [wsD 1MB][wsA 4MB][flags 8KB]
    float*        wsD   = (float*)d_ws;
    float4*       wsA   = (float4*)((char*)d_ws + (1u << 20));
    unsigned int* flags = (unsigned int*)((char*)d_ws + (5u << 20));

    qa_fused12<<<dim3(2048), dim3(256), 0, stream>>>(x, Wq, Wk, Wv, Wo,
                                                     wsD, wsA, flags, out);
}

// Round 8
// 96.805 us; speedup vs baseline: 1.5169x; 1.5169x over previous
//
#include <hip/hip_runtime.h>

// QuantumAttention: B=8, S=2048, E=8, H=2, D=4, NQ=8
//
// Fixed-cost ledger (R5..R12, rocprof-anchored): total = fill 40.5 +
// ~17.5us fixed harness/graph overhead (INDEPENDENT of node count --
// falsified per-node model via R12) + attn + merge. R12 cross-block fusion:
// 89us kernel (XCD-noncoherent flag traffic + 128 spinning blocks) --
// reverted. Broadcast mechanisms: LDS 26us < DPP ~39 < readlane ~64.
// attn LDS model: reads/CU = 4096/M' ... M=2: 20.5us LDS pipe (bound);
// M=4: 10.2us LDS, 8.5us VALU. M=4 failed at (256,8) cap=64 VGPR (R10,
// spill, +9us) and at (256,4) = 4 w/SIMD (R5, latency, 27us).
// R13: M=4 at (256,6): cap 80 VGPR (fits ~60-70 live), 6 waves/SIMD.
// Geometry = R10 (2048 blocks, 256 rows/block, 128-j windows, 32 j/wave);
// staging/reduce style = R9 (1 thread/j, separate LDS arrays, no alias).
// Predict attn ~13-16us, total ~74-78.
//
// Quantum circuit closed-form: c_w = cos(tok[w]+tok[w%4]);
// z[0]=c1..c7, z[q>=1]=c0..cq. Softmax one-pass (scores bounded, fp32 safe);
// 0.5*log2(e) folded into Wq so inner exp is bare v_exp_f32 (exp2).

#define SS 2048
#define EE 8

// grid 2048: bid = b<<8 | h<<7 | rt<<4 | jw.  256 threads = 4 waves.
// Block: rows rt*256..+255 (4 per lane, stride 64), j-window jw*128..+127
// (32 j per wave). All 4 waves share the same 256 rows.
extern "C" __global__ __launch_bounds__(256, 6)
void qa_attn13(const float* __restrict__ x, const float* __restrict__ Wq,
               const float* __restrict__ Wk, const float* __restrict__ Wv,
               float* __restrict__ wsD, float4* __restrict__ wsA) {
    __shared__ float wrow[96];                      // wq'(scaled), wk, wv
    __shared__ __align__(16) float4 kv4[256];       // 128 j x {K4,V4} = 4KB
    __shared__ float rden[3 * 256];                 // waves 1..3 partials, 3KB
    __shared__ __align__(16) float4 racc[3 * 256];  // 12KB

    const int bid = blockIdx.x;
    const int jw = bid & 15, rt = (bid >> 4) & 7, h = (bid >> 7) & 1, b = bid >> 8;
    const int tid = threadIdx.x, lane = tid & 63, w = tid >> 6;

    if (tid < 96) {
        const int grp = tid >> 5, d = (tid >> 3) & 3, e = tid & 7;
        const float* W = (grp == 0) ? Wq : (grp == 1 ? Wk : Wv);
        float val = W[(h * 4 + d) * EE + e];
        if (grp == 0) val *= 0.72134752044f;   // 0.5 * log2(e)
        wrow[tid] = val;
    }
    __syncthreads();   // wrow ready

    // ---- stage K,V for the 128-j window (one j per thread, tid<128) ----
    if (tid < 128) {
        const int j = jw * 128 + tid;
        const float* xp = x + ((size_t)(b * SS + j)) * EE;
        float xv[8];
        *(float4*)&xv[0] = *(const float4*)xp;
        *(float4*)&xv[4] = *(const float4*)(xp + 4);
        float kk[4], vv[4];
        #pragma unroll
        for (int d = 0; d < 4; ++d) {
            float sk = 0.f, sv = 0.f;
            #pragma unroll
            for (int e = 0; e < 8; ++e) {
                sk += xv[e] * wrow[32 + d * 8 + e];
                sv += xv[e] * wrow[64 + d * 8 + e];
            }
            kk[d] = sk; vv[d] = sv;
        }
        kv4[tid * 2]     = make_float4(kk[0], kk[1], kk[2], kk[3]);
        kv4[tid * 2 + 1] = make_float4(vv[0], vv[1], vv[2], vv[3]);
    }

    // ---- q' (log2-scaled) for this lane's 4 rows (stride 64) ----
    float q[4][4];
    const int row0 = rt * 256 + lane;
    #pragma unroll
    for (int m = 0; m < 4; ++m) {
        const float* xp = x + ((size_t)(b * SS + row0 + m * 64)) * EE;
        float xv[8];
        *(float4*)&xv[0] = *(const float4*)xp;
        *(float4*)&xv[4] = *(const float4*)(xp + 4);
        #pragma unroll
        for (int d = 0; d < 4; ++d) {
            float s = 0.f;
            #pragma unroll
            for (int e = 0; e < 8; ++e) s += xv[e] * wrow[d * 8 + e];
            q[m][d] = s;
        }
    }
    __syncthreads();   // kv4 ready

    // ---- 32-j slice for this wave, 4 rows per lane ----
    float den[4] = {};
    float acc[4][4] = {};
    const float4* kvp = &kv4[w * 64];   // 32 j, 2 float4 each
    #pragma unroll 2
    for (int jl = 0; jl < 32; ++jl) {
        const float4 kk = kvp[jl * 2];      // wave-broadcast
        const float4 vv = kvp[jl * 2 + 1];
        #pragma unroll
        for (int m = 0; m < 4; ++m) {
            const float s = q[m][0] * kk.x + q[m][1] * kk.y
                          + q[m][2] * kk.z + q[m][3] * kk.w;
            const float e = __builtin_amdgcn_exp2f(s);
            den[m] += e;
            acc[m][0] += e * vv.x; acc[m][1] += e * vv.y;
            acc[m][2] += e * vv.z; acc[m][3] += e * vv.w;
        }
    }

    // ---- single-stage reduce: waves 1..3 park, wave 0 merges + writes ----
    if (w > 0) {
        #pragma unroll
        for (int m = 0; m < 4; ++m) {
            rden[(w - 1) * 256 + lane + m * 64] = den[m];
            racc[(w - 1) * 256 + lane + m * 64] =
                make_float4(acc[m][0], acc[m][1], acc[m][2], acc[m][3]);
        }
    }
    __syncthreads();
    if (w == 0) {
        #pragma unroll
        for (int m = 0; m < 4; ++m) {
            const int r = lane + m * 64;
            float d = den[m] + rden[r] + rden[256 + r] + rden[512 + r];
            float4 a1 = racc[r], a2 = racc[256 + r], a3 = racc[512 + r];
            float4 a = make_float4(acc[m][0] + a1.x + a2.x + a3.x,
                                   acc[m][1] + a1.y + a2.y + a3.y,
                                   acc[m][2] + a1.z + a2.z + a3.z,
                                   acc[m][3] + a1.w + a2.w + a3.w);
            const size_t idx = ((size_t)((b * 2 + h) * 16 + jw)) * SS + row0 + m * 64;
            wsD[idx] = d;
            wsA[idx] = a;
        }
    }
}

// ---- merge + quantum: 2 threads/token (one per head), shfl_xor exchange.
// 128 blocks x 256 threads; 16 slices per (token, head). (= merge10)
extern "C" __global__ __launch_bounds__(256)
void qa_merge13(const float* __restrict__ wsD, const float4* __restrict__ wsA,
                const float* __restrict__ Wo, float* __restrict__ out) {
    __shared__ float wo[64];
    const int tid = threadIdx.x;
    if (tid < 64) wo[tid] = Wo[tid];
    __syncthreads();

    const int gt = blockIdx.x * 256 + tid;   // 0..32767
    const int g = gt >> 1, h = gt & 1;       // token, head
    const int b = g >> 11, s = g & 2047;

    float den = 0.f, a0 = 0.f, a1 = 0.f, a2 = 0.f, a3 = 0.f;
    #pragma unroll
    for (int sl = 0; sl < 16; ++sl) {
        const size_t idx = ((size_t)((b * 2 + h) * 16 + sl)) * SS + s;
        den += wsD[idx];
        const float4 p = wsA[idx];
        a0 += p.x; a1 += p.y; a2 += p.z; a3 += p.w;
    }
    const float inv = 1.f / den;
    float own[4] = {a0 * inv, a1 * inv, a2 * inv, a3 * inv};
    float oth[4];
    #pragma unroll
    for (int c = 0; c < 4; ++c) oth[c] = __shfl_xor(own[c], 1);

    float tok[8];
    #pragma unroll
    for (int c = 0; c < 4; ++c) {
        tok[c]     = h ? oth[c] : own[c];
        tok[4 + c] = h ? own[c] : oth[c];
    }

    float cc[8];
    #pragma unroll
    for (int ww = 0; ww < 8; ++ww) cc[ww] = __cosf(tok[ww] + tok[ww & 3]);

    float z[8];
    float p = 1.f;
    #pragma unroll
    for (int qq = 1; qq < 8; ++qq) { p *= cc[qq]; z[qq] = p; }
    z[0] = p;                       // c1..c7
    #pragma unroll
    for (int qq = 1; qq < 8; ++qq) z[qq] *= cc[0];   // c0..cq

    // this thread writes outputs f = h*4 .. h*4+3
    float y[4];
    #pragma unroll
    for (int f = 0; f < 4; ++f) {
        float sum = 0.f;
        #pragma unroll
        for (int qq = 0; qq < 8; ++qq) sum += z[qq] * wo[(h * 4 + f) * 8 + qq];
        y[f] = sum;
    }
    float4* op = (float4*)(out + (size_t)g * 8) + h;
    *op = make_float4(y[0], y[1], y[2], y[3]);
}

extern "C" void kernel_launch(void* const* d_in, const int* in_sizes, int n_in,
                              void* d_out, int out_size, void* d_ws, size_t ws_size,
                              hipStream_t stream) {
    const float* x  = (const float*)d_in[0];
    const float* Wq = (const float*)d_in[1];
    const float* Wk = (const float*)d_in[2];
    const float* Wv = (const float*)d_in[3];
    const float* Wo = (const float*)d_in[4];
    float* out = (float*)d_out;

    float*  wsD = (float*)d_ws;                          // 16*16*2048 floats = 2 MB
    float4* wsA = (float4*)((char*)d_ws + (16 * 16 * 2048) * sizeof(float)); // 8 MB

    qa_attn13<<<dim3(2048), dim3(256), 0, stream>>>(x, Wq, Wk, Wv, wsD, wsA);
    qa_merge13<<<dim3(128), dim3(256), 0, stream>>>(wsD, wsA, Wo, out);
}

// Round 9
// 83.791 us; speedup vs baseline: 1.7525x; 1.1553x over previous
//
#include <hip/hip_runtime.h>

// QuantumAttention: B=8, S=2048, E=8, H=2, D=4, NQ=8
//
// Fixed-cost ledger (rocprof-anchored): total = fill ~40.5-44 + ~17.5us
// fixed harness/graph overhead (node-count-independent, falsified per-node
// model via R12) + attn + merge~2.6. Best attn = attn9 (M=2, LDS broadcast,
// 2048 blk, 8 w/SIMD) = 26us. Falsified models: LDS-pipe 1/M scaling (R10/
// R13 M=4 variants all ~34, worse); readlane (R7, VALU->SGPR hazard, 63);
// DPP rotate (R11, serial dep, 39); cross-block fusion (R12, XCD-noncoherent
// flags, 89). Scalar VALU floor ~7.7us; attn9 runs ~35-50% issue-occupancy.
// R14: halve inner-loop VALU issue via packed FP32 (v_pk_fma_f32): pack the
// m-dimension (2 rows) into v2f halves; K/V splat into both halves. Per j:
// 18 VALU + 2 trans -> 9 pk + 2 trans. Each half = identical fma chain =>
// bit-identical per row. All else byte-identical to R9.
//
// Quantum circuit closed-form: c_w = cos(tok[w]+tok[w%4]);
// z[0]=c1..c7, z[q>=1]=c0..cq. Softmax one-pass (scores bounded, fp32 safe);
// 0.5*log2(e) folded into Wq so inner exp is bare v_exp_f32 (exp2).

#define SS 2048
#define EE 8

typedef float v2f __attribute__((ext_vector_type(2)));

// grid 2048: bid = b<<8 | h<<7 | rt<<3 | jw.  256 threads = 4 waves.
// Block: rows rt*128..+127 (2 per lane), j-window jw*256..+255 (64 per wave).
extern "C" __global__ __launch_bounds__(256, 8)
void qa_attn14(const float* __restrict__ x, const float* __restrict__ Wq,
               const float* __restrict__ Wk, const float* __restrict__ Wv,
               float* __restrict__ wsD, float4* __restrict__ wsA) {
    __shared__ float wrow[96];                    // wq'(scaled), wk, wv
    __shared__ __align__(16) float4 kv4[512];     // 256 j x {K4,V4} = 8 KB
    __shared__ float rden[3 * 128];               // waves 1..3 partials
    __shared__ __align__(16) float4 racc[3 * 128];// 6 KB

    const int bid = blockIdx.x;
    const int jw = bid & 7, rt = (bid >> 3) & 15, h = (bid >> 7) & 1, b = bid >> 8;
    const int tid = threadIdx.x, lane = tid & 63, w = tid >> 6;

    if (tid < 96) {
        const int grp = tid >> 5, d = (tid >> 3) & 3, e = tid & 7;
        const float* W = (grp == 0) ? Wq : (grp == 1 ? Wk : Wv);
        float val = W[(h * 4 + d) * EE + e];
        if (grp == 0) val *= 0.72134752044f;   // 0.5 * log2(e)
        wrow[tid] = val;
    }
    __syncthreads();   // wrow ready

    // ---- stage K,V for the 256-j window (one j per thread) ----
    {
        const int j = jw * 256 + tid;
        const float* xp = x + ((size_t)(b * SS + j)) * EE;
        float xv[8];
        *(float4*)&xv[0] = *(const float4*)xp;
        *(float4*)&xv[4] = *(const float4*)(xp + 4);
        float kk[4], vv[4];
        #pragma unroll
        for (int d = 0; d < 4; ++d) {
            float sk = 0.f, sv = 0.f;
            #pragma unroll
            for (int e = 0; e < 8; ++e) {
                sk += xv[e] * wrow[32 + d * 8 + e];
                sv += xv[e] * wrow[64 + d * 8 + e];
            }
            kk[d] = sk; vv[d] = sv;
        }
        kv4[tid * 2]     = make_float4(kk[0], kk[1], kk[2], kk[3]);
        kv4[tid * 2 + 1] = make_float4(vv[0], vv[1], vv[2], vv[3]);
    }

    // ---- q' (log2-scaled) for this lane's 2 rows ----
    float q[2][4];
    const int row0 = rt * 128 + lane;
    #pragma unroll
    for (int m = 0; m < 2; ++m) {
        const float* xp = x + ((size_t)(b * SS + row0 + m * 64)) * EE;
        float xv[8];
        *(float4*)&xv[0] = *(const float4*)xp;
        *(float4*)&xv[4] = *(const float4*)(xp + 4);
        #pragma unroll
        for (int d = 0; d < 4; ++d) {
            float s = 0.f;
            #pragma unroll
            for (int e = 0; e < 8; ++e) s += xv[e] * wrow[d * 8 + e];
            q[m][d] = s;
        }
    }
    __syncthreads();   // kv4 ready

    // ---- 64-j slice for this wave, 2 rows per lane, m-packed fp32 ----
    v2f qp[4];
    #pragma unroll
    for (int d = 0; d < 4; ++d) qp[d] = (v2f){q[0][d], q[1][d]};
    v2f denp = (v2f){0.f, 0.f};
    v2f accp[4];
    #pragma unroll
    for (int c = 0; c < 4; ++c) accp[c] = (v2f){0.f, 0.f};

    const float4* kvp = &kv4[w * 128];
    #pragma unroll 2
    for (int jl = 0; jl < 64; ++jl) {
        const float4 kk = kvp[jl * 2];      // wave-broadcast
        const float4 vv = kvp[jl * 2 + 1];
        // dot: identical mul+fma chain per half as scalar version
        v2f s = qp[0] * (v2f){kk.x, kk.x};
        s = __builtin_elementwise_fma(qp[1], (v2f){kk.y, kk.y}, s);
        s = __builtin_elementwise_fma(qp[2], (v2f){kk.z, kk.z}, s);
        s = __builtin_elementwise_fma(qp[3], (v2f){kk.w, kk.w}, s);
        v2f e;
        e.x = __builtin_amdgcn_exp2f(s.x);
        e.y = __builtin_amdgcn_exp2f(s.y);
        denp += e;                           // v_pk_add_f32
        accp[0] = __builtin_elementwise_fma(e, (v2f){vv.x, vv.x}, accp[0]);
        accp[1] = __builtin_elementwise_fma(e, (v2f){vv.y, vv.y}, accp[1]);
        accp[2] = __builtin_elementwise_fma(e, (v2f){vv.z, vv.z}, accp[2]);
        accp[3] = __builtin_elementwise_fma(e, (v2f){vv.w, vv.w}, accp[3]);
    }

    float den[2] = {denp.x, denp.y};
    float acc[2][4];
    #pragma unroll
    for (int c = 0; c < 4; ++c) { acc[0][c] = accp[c].x; acc[1][c] = accp[c].y; }

    // ---- single-stage reduce: waves 1..3 park, wave 0 merges + writes ----
    if (w > 0) {
        #pragma unroll
        for (int m = 0; m < 2; ++m) {
            rden[(w - 1) * 128 + lane + m * 64] = den[m];
            racc[(w - 1) * 128 + lane + m * 64] =
                make_float4(acc[m][0], acc[m][1], acc[m][2], acc[m][3]);
        }
    }
    __syncthreads();
    if (w == 0) {
        #pragma unroll
        for (int m = 0; m < 2; ++m) {
            const int r = lane + m * 64;
            float d = den[m] + rden[r] + rden[128 + r] + rden[256 + r];
            float4 a1 = racc[r], a2 = racc[128 + r], a3 = racc[256 + r];
            float4 a = make_float4(acc[m][0] + a1.x + a2.x + a3.x,
                                   acc[m][1] + a1.y + a2.y + a3.y,
                                   acc[m][2] + a1.z + a2.z + a3.z,
                                   acc[m][3] + a1.w + a2.w + a3.w);
            const size_t idx = ((size_t)((b * 2 + h) * 8 + jw)) * SS + row0 + m * 64;
            wsD[idx] = d;
            wsA[idx] = a;
        }
    }
}

// ---- merge + quantum: 2 threads/token (one per head), shfl_xor exchange.
// UNCHANGED from R9 (bit-identical).
extern "C" __global__ __launch_bounds__(256)
void qa_merge14(const float* __restrict__ wsD, const float4* __restrict__ wsA,
                const float* __restrict__ Wo, float* __restrict__ out) {
    __shared__ float wo[64];
    const int tid = threadIdx.x;
    if (tid < 64) wo[tid] = Wo[tid];
    __syncthreads();

    const int gt = blockIdx.x * 256 + tid;   // 0..32767
    const int g = gt >> 1, h = gt & 1;       // token, head
    const int b = g >> 11, s = g & 2047;

    float den = 0.f, a0 = 0.f, a1 = 0.f, a2 = 0.f, a3 = 0.f;
    #pragma unroll
    for (int sl = 0; sl < 8; ++sl) {
        const size_t idx = ((size_t)((b * 2 + h) * 8 + sl)) * SS + s;
        den += wsD[idx];
        const float4 p = wsA[idx];
        a0 += p.x; a1 += p.y; a2 += p.z; a3 += p.w;
    }
    const float inv = 1.f / den;
    float own[4] = {a0 * inv, a1 * inv, a2 * inv, a3 * inv};
    float oth[4];
    #pragma unroll
    for (int c = 0; c < 4; ++c) oth[c] = __shfl_xor(own[c], 1);

    float tok[8];
    #pragma unroll
    for (int c = 0; c < 4; ++c) {
        tok[c]     = h ? oth[c] : own[c];
        tok[4 + c] = h ? own[c] : oth[c];
    }

    float cc[8];
    #pragma unroll
    for (int ww = 0; ww < 8; ++ww) cc[ww] = __cosf(tok[ww] + tok[ww & 3]);

    float z[8];
    float p = 1.f;
    #pragma unroll
    for (int qq = 1; qq < 8; ++qq) { p *= cc[qq]; z[qq] = p; }
    z[0] = p;                       // c1..c7
    #pragma unroll
    for (int qq = 1; qq < 8; ++qq) z[qq] *= cc[0];   // c0..cq

    // this thread writes outputs f = h*4 .. h*4+3
    float y[4];
    #pragma unroll
    for (int f = 0; f < 4; ++f) {
        float sum = 0.f;
        #pragma unroll
        for (int qq = 0; qq < 8; ++qq) sum += z[qq] * wo[(h * 4 + f) * 8 + qq];
        y[f] = sum;
    }
    float4* op = (float4*)(out + (size_t)g * 8) + h;
    *op = make_float4(y[0], y[1], y[2], y[3]);
}

extern "C" void kernel_launch(void* const* d_in, const int* in_sizes, int n_in,
                              void* d_out, int out_size, void* d_ws, size_t ws_size,
                              hipStream_t stream) {
    const float* x  = (const float*)d_in[0];
    const float* Wq = (const float*)d_in[1];
    const float* Wk = (const float*)d_in[2];
    const float* Wv = (const float*)d_in[3];
    const float* Wo = (const float*)d_in[4];
    float* out = (float*)d_out;

    float*  wsD = (float*)d_ws;                          // 16*8*2048 floats = 1 MB
    float4* wsA = (float4*)((char*)d_ws + (16 * 8 * 2048) * sizeof(float)); // 4 MB

    qa_attn14<<<dim3(2048), dim3(256), 0, stream>>>(x, Wq, Wk, Wv, wsD, wsA);
    qa_merge14<<<dim3(128), dim3(256), 0, stream>>>(wsD, wsA, Wo, out);
}